// Round 1
// baseline (1490.588 us; speedup 1.0000x reference)
//
#include <hip/hip_runtime.h>
#include <cfloat>
#include <cmath>

#define HC 80   // H*C
#define HH 8    // heads
#define CC 10   // channels per head

// ---------------- CSR build ----------------

__global__ void hist_kernel(const int* __restrict__ dst, int* __restrict__ counts, int E) {
    int i = blockIdx.x * blockDim.x + threadIdx.x;
    int stride = gridDim.x * blockDim.x;
    for (; i < E; i += stride) atomicAdd(&counts[dst[i]], 1);
}

// single-block exclusive scan over n elements, writes out[0..n] (out[n] = total)
__global__ void scan_kernel(const int* __restrict__ in, int* __restrict__ out, int n) {
    const int B = 1024;
    __shared__ int buf[B];
    __shared__ int carry;
    if (threadIdx.x == 0) carry = 0;
    __syncthreads();
    for (int base = 0; base < n; base += B) {
        int i = base + (int)threadIdx.x;
        int v = (i < n) ? in[i] : 0;
        buf[threadIdx.x] = v;
        __syncthreads();
        for (int off = 1; off < B; off <<= 1) {
            int t = (threadIdx.x >= (unsigned)off) ? buf[threadIdx.x - off] : 0;
            __syncthreads();
            buf[threadIdx.x] += t;
            __syncthreads();
        }
        int incl = buf[threadIdx.x];
        int total = buf[B - 1];
        int c = carry;
        if (i < n) out[i] = c + incl - v;
        __syncthreads();
        if (threadIdx.x == 0) carry = c + total;
        __syncthreads();
    }
    if (threadIdx.x == 0) out[n] = carry;
}

__global__ void scatter_kernel(const int* __restrict__ src, const int* __restrict__ dst,
                               int* __restrict__ cursor, int* __restrict__ csr, int E) {
    int i = blockIdx.x * blockDim.x + threadIdx.x;
    int stride = gridDim.x * blockDim.x;
    for (; i < E; i += stride) {
        int p = atomicAdd(&cursor[dst[i]], 1);
        csr[p] = src[i];
    }
}

// ---------------- dual GEMM: Yl = X@Wl, Yr = X@Wr  (X:[N,K], W:[K,80]) ----------------

__device__ __forceinline__ void fma4(float4& a, float s, const float4 w) {
    a.x += s * w.x; a.y += s * w.y; a.z += s * w.z; a.w += s * w.w;
}

__global__ void gemm_dual(const float* __restrict__ X,
                          const float* __restrict__ Wl, const float* __restrict__ Wr,
                          float* __restrict__ Yl, float* __restrict__ Yr, int N, int K) {
    int t = blockIdx.x * blockDim.x + threadIdx.x;
    if (t >= N * 20) return;
    int n = t / 20;
    int jg = (t - n * 20) * 4;
    const float4* X4 = (const float4*)(X + (size_t)n * K);
    float4 al = {0.f, 0.f, 0.f, 0.f};
    float4 ar = {0.f, 0.f, 0.f, 0.f};
    int K4 = K >> 2;
    for (int k4 = 0; k4 < K4; ++k4) {
        float4 xv = X4[k4];
        int k = k4 << 2;
        const float* wl = Wl + (size_t)k * HC + jg;
        const float* wr = Wr + (size_t)k * HC + jg;
        fma4(al, xv.x, *(const float4*)(wl));
        fma4(al, xv.y, *(const float4*)(wl + HC));
        fma4(al, xv.z, *(const float4*)(wl + 2 * HC));
        fma4(al, xv.w, *(const float4*)(wl + 3 * HC));
        fma4(ar, xv.x, *(const float4*)(wr));
        fma4(ar, xv.y, *(const float4*)(wr + HC));
        fma4(ar, xv.z, *(const float4*)(wr + 2 * HC));
        fma4(ar, xv.w, *(const float4*)(wr + 3 * HC));
    }
    *(float4*)(Yl + (size_t)n * HC + jg) = al;
    *(float4*)(Yr + (size_t)n * HC + jg) = ar;
}

// ---------------- fused per-node attention + softmax + aggregate + elu ----------------
// block = 128 threads = 8 head-groups of 16 lanes (10 active each).

__global__ __launch_bounds__(128) void aggregate_kernel(
    const float* __restrict__ xl, const float* __restrict__ xr,
    const int* __restrict__ csr, const int* __restrict__ offsets,
    const float* __restrict__ att, const float* __restrict__ bias,
    float* __restrict__ xout, int N) {
    int n = blockIdx.x;
    int tid = threadIdx.x;
    int h = tid >> 4;
    int c = tid & 15;
    bool active = c < CC;
    int d = h * CC + (active ? c : CC - 1);   // clamped for safe loads
    float mask = active ? 1.f : 0.f;
    float attv = att[d] * mask;               // inactive lanes contribute 0 to e
    float xrv = xr[(size_t)n * HC + d];
    int beg = offsets[n], end = offsets[n + 1];

    float m = -FLT_MAX, s = 0.f, acc = 0.f;
    for (int i = beg - 1; i < end; ++i) {
        int src = (i < beg) ? n : csr[i];     // iteration -1 = self loop
        float xlv = xl[(size_t)src * HC + d];
        float t = xlv + xrv;
        t = (t > 0.f) ? t : 0.2f * t;         // leaky_relu
        float ev = t * attv;
        ev += __shfl_xor(ev, 8, 16);          // sum over the 16-lane head group
        ev += __shfl_xor(ev, 4, 16);
        ev += __shfl_xor(ev, 2, 16);
        ev += __shfl_xor(ev, 1, 16);
        float mn = fmaxf(m, ev);
        float sc = __expf(m - mn);
        float p = __expf(ev - mn);
        s = s * sc + p;
        acc = acc * sc + p * xlv;
        m = mn;
    }
    if (active) {
        float o = acc / s + bias[d];
        xout[(size_t)n * HC + h * CC + c] = (o > 0.f) ? o : (__expf(o) - 1.f);  // elu
    }
}

extern "C" void kernel_launch(void* const* d_in, const int* in_sizes, int n_in,
                              void* d_out, int out_size, void* d_ws, size_t ws_size,
                              hipStream_t stream) {
    int N = out_size / HC;       // 100000
    int E = in_sizes[1] / 2;     // 1000000
    int F = in_sizes[0] / N;     // 128

    const float* x   = (const float*)d_in[0];
    const int*   ei  = (const int*)d_in[1];
    const float* Wl[3]  = {(const float*)d_in[2], (const float*)d_in[6],  (const float*)d_in[10]};
    const float* Wr[3]  = {(const float*)d_in[3], (const float*)d_in[7],  (const float*)d_in[11]};
    const float* att[3] = {(const float*)d_in[4], (const float*)d_in[8],  (const float*)d_in[12]};
    const float* bb[3]  = {(const float*)d_in[5], (const float*)d_in[9],  (const float*)d_in[13]};

    size_t NF = (size_t)N * HC;
    float* xl = (float*)d_ws;
    float* xr = xl + NF;
    float* xb = xr + NF;
    int* counts  = (int*)(xb + NF);
    int* offsets = counts + (N + 1);
    int* cursor  = offsets + (N + 1);
    int* csr     = cursor + N;

    const int* srcv = ei;
    const int* dstv = ei + E;

    // build dst-CSR (self loops handled implicitly in aggregate)
    hipMemsetAsync(counts, 0, (size_t)(N + 1) * sizeof(int), stream);
    hist_kernel<<<1024, 256, 0, stream>>>(dstv, counts, E);
    scan_kernel<<<1, 1024, 0, stream>>>(counts, offsets, N);
    hipMemcpyAsync(cursor, offsets, (size_t)N * sizeof(int), hipMemcpyDeviceToDevice, stream);
    scatter_kernel<<<1024, 256, 0, stream>>>(srcv, dstv, cursor, csr, E);

    for (int l = 0; l < 3; ++l) {
        const float* xin = (l == 0) ? x : xb;
        int K = (l == 0) ? F : HC;
        int T = N * 20;
        gemm_dual<<<(T + 255) / 256, 256, 0, stream>>>(xin, Wl[l], Wr[l], xl, xr, N, K);
        float* xout = (l == 2) ? (float*)d_out : xb;
        aggregate_kernel<<<N, 128, 0, stream>>>(xl, xr, csr, offsets, att[l], bb[l], xout, N);
    }
}